// Round 1
// baseline (1032.509 us; speedup 1.0000x reference)
//
#include <hip/hip_runtime.h>

#define N_RES 768
#define S_MSA 512
#define TF_D 21
#define MSA_D 49
#define CZ 128
#define CM 256

// ---------------------------------------------------------------------------
// k_embed: three tiny matmuls from target_feat [N,21]:
//   tfi[n][c] = sum_k tf[n][k] w_i[k][c] + b_i[c] + b_rel[c]   (c<128)
//   tfj[n][c] = sum_k tf[n][k] w_j[k][c] + b_j[c]              (c<128)
//   tfm[n][c] = sum_k tf[n][k] w_m[k][c] + b_m[c] + b_msa[c]   (c<256)
// One block per residue n, 512 threads: [0,128)->tfi, [128,256)->tfj,
// [256,512)->tfm. Biases folded here so downstream kernels are pure adds.
// ---------------------------------------------------------------------------
__global__ __launch_bounds__(512) void k_embed(
    const float* __restrict__ tf,
    const float* __restrict__ w_i, const float* __restrict__ b_i,
    const float* __restrict__ w_j, const float* __restrict__ b_j,
    const float* __restrict__ w_m, const float* __restrict__ b_m,
    const float* __restrict__ b_rel, const float* __restrict__ b_msa,
    float* __restrict__ tfi, float* __restrict__ tfj, float* __restrict__ tfm)
{
    const int n = blockIdx.x;
    const int t = threadIdx.x;
    float a[TF_D];
#pragma unroll
    for (int k = 0; k < TF_D; ++k) a[k] = tf[n * TF_D + k];  // uniform -> s_load

    if (t < CZ) {
        const int c = t;
        float acc = b_i[c] + b_rel[c];
#pragma unroll
        for (int k = 0; k < TF_D; ++k) acc = fmaf(a[k], w_i[k * CZ + c], acc);
        tfi[n * CZ + c] = acc;
    } else if (t < 2 * CZ) {
        const int c = t - CZ;
        float acc = b_j[c];
#pragma unroll
        for (int k = 0; k < TF_D; ++k) acc = fmaf(a[k], w_j[k * CZ + c], acc);
        tfj[n * CZ + c] = acc;
    } else {
        const int c = t - 2 * CZ;
        float acc = b_m[c] + b_msa[c];
#pragma unroll
        for (int k = 0; k < TF_D; ++k) acc = fmaf(a[k], w_m[k * CM + c], acc);
        tfm[n * CM + c] = acc;
    }
}

// ---------------------------------------------------------------------------
// k_pair: pair_emb[i][j][c] =
//   w_rel[pos(i,j)][c] + ent(i,j)*w_rel[66][c] + w_rel[67+chain(i,j)][c]
//   + tfi[i][c] + tfj[j][c]
// (bias b_relpos already folded into tfi). The one-hot argmin over integer
// offsets is the identity, so the relpos "matmul" collapses to 3 gathers.
// 256 threads/block = 8 pairs/block, 32 lanes x float4 per pair.
// ---------------------------------------------------------------------------
__global__ __launch_bounds__(256) void k_pair(
    const int* __restrict__ res, const int* __restrict__ sym,
    const int* __restrict__ asym, const int* __restrict__ ent,
    const float* __restrict__ w_rel,
    const float* __restrict__ tfi, const float* __restrict__ tfj,
    float* __restrict__ out)
{
    const int sub  = threadIdx.x >> 5;   // which pair within block, 0..7
    const int lane = threadIdx.x & 31;   // float4 index within row, 0..31
    const int p = blockIdx.x * 8 + sub;  // grid sized exactly N*N/8
    const int i = p / N_RES;
    const int j = p - i * N_RES;

    int off = res[i] - res[j] + 32;
    off = min(max(off, 0), 64);
    const int pos = (asym[i] == asym[j]) ? off : 65;

    const int entv = ent[i] - sym[j];
    int cc = sym[i] - sym[j] + 2;
    cc = min(max(cc, 0), 4);
    const int chain = (entv != 0) ? cc : 5;
    const float entf = (float)entv;

    const int c = lane * 4;
    const float4 wp = *(const float4*)(w_rel + pos * CZ + c);
    const float4 we = *(const float4*)(w_rel + 66 * CZ + c);
    const float4 wc = *(const float4*)(w_rel + (67 + chain) * CZ + c);
    const float4 ti = *(const float4*)(tfi + i * CZ + c);
    const float4 tj = *(const float4*)(tfj + j * CZ + c);

    float4 o;
    o.x = wp.x + entf * we.x + wc.x + ti.x + tj.x;
    o.y = wp.y + entf * we.y + wc.y + ti.y + tj.y;
    o.z = wp.z + entf * we.z + wc.z + ti.z + tj.z;
    o.w = wp.w + entf * we.w + wc.w + ti.w + tj.w;
    *(float4*)(out + (size_t)p * CZ + c) = o;
}

// ---------------------------------------------------------------------------
// k_msa: out[row][c] = sum_k msa[row][k] * w[k][c] + tfm[row % N][c]
// (both biases folded into tfm). Thread c holds w[:, c] in 49 VGPRs for its
// whole lifetime; per-row activations are wave-uniform reads (scalarizable).
// Grid-stride over the 393216 rows amortizes the w preload.
// ---------------------------------------------------------------------------
__global__ __launch_bounds__(256) void k_msa(
    const float* __restrict__ msa,
    const float* __restrict__ w,
    const float* __restrict__ tfm,
    float* __restrict__ out)
{
    const int c = threadIdx.x;
    float wr[MSA_D];
#pragma unroll
    for (int k = 0; k < MSA_D; ++k) wr[k] = w[k * CM + c];

    const int nrows = S_MSA * N_RES;
    for (int row = blockIdx.x; row < nrows; row += gridDim.x) {
        const float* __restrict__ ar = msa + (size_t)row * MSA_D;
        float av[MSA_D];
#pragma unroll
        for (int k = 0; k < MSA_D; ++k) av[k] = ar[k];  // uniform -> s_load

        const int n = row % N_RES;
        float acc = tfm[n * CM + c];
#pragma unroll
        for (int k = 0; k < MSA_D; ++k) acc = fmaf(av[k], wr[k], acc);
        out[(size_t)row * CM + c] = acc;
    }
}

// ---------------------------------------------------------------------------
extern "C" void kernel_launch(void* const* d_in, const int* in_sizes, int n_in,
                              void* d_out, int out_size, void* d_ws, size_t ws_size,
                              hipStream_t stream) {
    const float* target = (const float*)d_in[0];
    const float* msa    = (const float*)d_in[1];
    const int*   res    = (const int*)d_in[2];
    const int*   sym    = (const int*)d_in[3];
    const int*   asym   = (const int*)d_in[4];
    const int*   ent    = (const int*)d_in[5];
    const float* w_i    = (const float*)d_in[6];
    const float* b_i    = (const float*)d_in[7];
    const float* w_j    = (const float*)d_in[8];
    const float* b_j    = (const float*)d_in[9];
    const float* w_m    = (const float*)d_in[10];
    const float* b_m    = (const float*)d_in[11];
    const float* w_msa  = (const float*)d_in[12];
    const float* b_msa  = (const float*)d_in[13];
    const float* w_rel  = (const float*)d_in[14];
    const float* b_rel  = (const float*)d_in[15];

    float* out_msa  = (float*)d_out;                              // [S,N,CM]
    float* out_pair = out_msa + (size_t)S_MSA * N_RES * CM;       // [N,N,CZ]

    float* tfi = (float*)d_ws;          // [N,CZ]  (+b_i +b_rel)
    float* tfj = tfi + N_RES * CZ;      // [N,CZ]  (+b_j)
    float* tfm = tfj + N_RES * CZ;      // [N,CM]  (+b_m +b_msa)

    hipLaunchKernelGGL(k_embed, dim3(N_RES), dim3(512), 0, stream,
                       target, w_i, b_i, w_j, b_j, w_m, b_m, b_rel, b_msa,
                       tfi, tfj, tfm);
    hipLaunchKernelGGL(k_msa, dim3(8192), dim3(256), 0, stream,
                       msa, w_msa, tfm, out_msa);
    hipLaunchKernelGGL(k_pair, dim3((N_RES * N_RES) / 8), dim3(256), 0, stream,
                       res, sym, asym, ent, w_rel, tfi, tfj, out_pair);
}